// Round 5
// baseline (441.578 us; speedup 1.0000x reference)
//
#include <hip/hip_runtime.h>
#include <math.h>

typedef unsigned short u16;
typedef __bf16 bf16x8 __attribute__((ext_vector_type(8)));
typedef float f32x4 __attribute__((ext_vector_type(4)));
typedef unsigned short u16x8 __attribute__((ext_vector_type(8)));

#define SHIFT 2

static __device__ __forceinline__ f32x4 mfma16(bf16x8 a, bf16x8 b, f32x4 c) {
  return __builtin_amdgcn_mfma_f32_16x16x32_bf16(a, b, c, 0, 0, 0);
}
static __device__ __forceinline__ u16 f2bf(float f) {
  unsigned u = __builtin_bit_cast(unsigned, f);
  unsigned r = u + 0x7fffu + ((u >> 16) & 1u);
  return (u16)(r >> 16);
}
static __device__ __forceinline__ float bf2f(u16 u) {
  unsigned v = (unsigned)u << 16;
  return __builtin_bit_cast(float, v);
}
static __device__ __forceinline__ void stage16(const u16* g, u16* lbase, int lane) {
#if __has_builtin(__builtin_amdgcn_global_load_lds)
  __builtin_amdgcn_global_load_lds(
      (const __attribute__((address_space(1))) unsigned int*)g,
      (__attribute__((address_space(3))) unsigned int*)lbase, 16, 0, 0);
#else
  *(u16x8*)(lbase + lane * 8) = *(const u16x8*)g;
#endif
}

// ---------------- workspace layout (bytes) ----------------
#define OFF_KVWT  ((size_t)0)                          // 384x192 bf16
#define OFF_PRWT  (OFF_KVWT + 384*192*2)               // 192x192
#define OFF_FC1WT (OFF_PRWT + 192*192*2)               // 768x192
#define OFF_FC2WT (OFF_FC1WT + 768*192*2)              // 192x768
#define OFF_SKW   (OFF_FC2WT + 192*768*2)              // 65536x192 bf16 (window order)
#define OFF_QW    (OFF_SKW + (size_t)65536*192*2)
#define OFF_KVB   (OFF_QW + (size_t)65536*192*2)       // 65536x384 bf16 (window order)
#define OFF_HN    (OFF_KVB + (size_t)65536*384*2)      // 65536x192 bf16 (natural)
#define OFF_PO    (OFF_HN + (size_t)65536*192*2)       // 65536x192 bf16 (natural)

// ---------------- K0: weight transpose + f32->bf16 ----------------
__global__ __launch_bounds__(256) void k_prep(
    const float* __restrict__ kv_w, const float* __restrict__ proj_w,
    const float* __restrict__ fc1_w, const float* __restrict__ fc2_w,
    u16* __restrict__ kvT, u16* __restrict__ prT,
    u16* __restrict__ f1T, u16* __restrict__ f2T) {
  int i = blockIdx.x * 256 + threadIdx.x;
  if (i < 192 * 384) kvT[(i % 384) * 192 + i / 384] = f2bf(kv_w[i]);
  if (i < 192 * 192) prT[(i % 192) * 192 + i / 192] = f2bf(proj_w[i]);
  if (i < 192 * 768) f1T[(i % 768) * 192 + i / 768] = f2bf(fc1_w[i]);
  if (i < 768 * 192) f2T[(i % 192) * 768 + i / 192] = f2bf(fc2_w[i]);
}

// ---------------- K1: LN + cyclic shift + window partition ----------------
__global__ __launch_bounds__(256) void k_ln_part(
    const float* __restrict__ skip, const float* __restrict__ x_up,
    const float* __restrict__ gam, const float* __restrict__ bet,
    u16* __restrict__ skw, u16* __restrict__ qw) {
  int row = blockIdx.x * 4 + (threadIdx.x >> 6);
  int lane = threadIdx.x & 63;
  const float* sp = skip + (size_t)row * 192;
  const float* qp = x_up + (size_t)row * 192;
  float sv[3], qv[3], ss = 0.f, qs = 0.f;
#pragma unroll
  for (int j = 0; j < 3; j++) {
    sv[j] = sp[lane + 64 * j]; qv[j] = qp[lane + 64 * j];
    ss += sv[j]; qs += qv[j];
  }
#pragma unroll
  for (int m = 1; m < 64; m <<= 1) { ss += __shfl_xor(ss, m, 64); qs += __shfl_xor(qs, m, 64); }
  float sm = ss * (1.f / 192.f), qm = qs * (1.f / 192.f);
  float s2 = 0.f, q2 = 0.f;
#pragma unroll
  for (int j = 0; j < 3; j++) { float d = sv[j] - sm; s2 += d * d; d = qv[j] - qm; q2 += d * d; }
#pragma unroll
  for (int m = 1; m < 64; m <<= 1) { s2 += __shfl_xor(s2, m, 64); q2 += __shfl_xor(q2, m, 64); }
  float sr = rsqrtf(s2 * (1.f / 192.f) + 1e-5f), qr = rsqrtf(q2 * (1.f / 192.f) + 1e-5f);
  int b = row >> 15, l = row & 32767;
  int s = l >> 10, h = (l >> 5) & 31, w = l & 31;
  int s_ = (s - SHIFT) & 31, h_ = (h - SHIFT) & 31, w_ = (w - SHIFT) & 31;
  int wIdx = ((s_ >> 2) * 8 + (h_ >> 2)) * 8 + (w_ >> 2);
  int n = ((s_ & 3) * 4 + (h_ & 3)) * 4 + (w_ & 3);
  size_t orow = ((size_t)(b * 512 + wIdx) * 64 + n) * 192;
  const float scale = 0.17677669529663687f;  // 32^-0.5
#pragma unroll
  for (int j = 0; j < 3; j++) {
    int cc = lane + 64 * j;
    float gg = gam[cc], bb = bet[cc];
    skw[orow + cc] = f2bf((sv[j] - sm) * sr * gg + bb);
    qw[orow + cc]  = f2bf(((qv[j] - qm) * qr * gg + bb) * scale);
  }
}

// ---------------- K2: kv GEMM, barrier-free wave-private ----------------
// Each wave owns 32 tokens x 192 out-cols (half of 384, by blockIdx.y).
// A-fragments direct from global (L1-served), weights stream from L2. No LDS.
__global__ __launch_bounds__(256, 3) void k_kv(
    const u16* __restrict__ A, const u16* __restrict__ BT,
    const float* __restrict__ bias, u16* __restrict__ outh) {
  int tid = threadIdx.x, l = tid & 63, wv = tid >> 6, g = l >> 4, c = l & 15;
  size_t tokbase = (size_t)blockIdx.x * 128 + wv * 32;
  int nb = blockIdx.y;  // col half
  f32x4 acc[12][2] = {};
#pragma unroll
  for (int ks = 0; ks < 6; ks++) {
    bf16x8 ha[2];
#pragma unroll
    for (int tf = 0; tf < 2; tf++)
      ha[tf] = *(const bf16x8*)&A[(tokbase + tf * 16 + c) * 192 + ks * 32 + g * 8];
#pragma unroll
    for (int of = 0; of < 12; of++) {
      bf16x8 wb = *(const bf16x8*)&BT[(size_t)(nb * 192 + of * 16 + c) * 192 + ks * 32 + g * 8];
#pragma unroll
      for (int tf = 0; tf < 2; tf++) acc[of][tf] = mfma16(ha[tf], wb, acc[of][tf]);
    }
  }
#pragma unroll
  for (int of = 0; of < 12; of++)
#pragma unroll
    for (int tf = 0; tf < 2; tf++) {
      int col = nb * 192 + of * 16 + c;
      float bb = bias[col];
#pragma unroll
      for (int r = 0; r < 4; r++) {
        size_t tok = tokbase + tf * 16 + g * 4 + r;
        outh[tok * 384 + col] = f2bf(acc[of][tf][r] + bb);
      }
    }
}

// ---------------- K3: fused attention + proj + residual + LN2 -----------------
__global__ __launch_bounds__(384) void k_attn_mega(
    const u16* __restrict__ qw, const u16* __restrict__ kvb,
    const float* __restrict__ rpb, const float* __restrict__ mask,
    const u16* __restrict__ prT, const float* __restrict__ proj_b,
    const float* __restrict__ x, const float* __restrict__ g2,
    const float* __restrict__ b2, u16* __restrict__ hn, u16* __restrict__ po) {
  __shared__ u16 lv[64 * 200];       // V tile (row-major, padded)
  __shared__ u16 lp[6][16 * 72];     // per-head P m-slice
  __shared__ u16 lo[64 * 200];       // attention output tile
  __shared__ float pf[64 * 16];      // LN partials
  int b_ = blockIdx.x, wIdx = b_ & 511;
  int tid = threadIdx.x, l = tid & 63, wv = tid >> 6, g = l >> 4, c = l & 15;
#pragma unroll
  for (int i = 0; i < 4; i++) {
    int cid = tid + i * 384;
    int row = cid / 24, ch = cid % 24;
    *(u16x8*)&lv[row * 200 + ch * 8] =
        *(const u16x8*)&kvb[((size_t)b_ * 64 + row) * 384 + 192 + ch * 8];
  }
  __syncthreads();
  int h = wv;
  bf16x8 qa[4], kb[4];
#pragma unroll
  for (int m = 0; m < 4; m++)
    qa[m] = *(const bf16x8*)&qw[((size_t)b_ * 64 + m * 16 + c) * 192 + h * 32 + g * 8];
#pragma unroll
  for (int n = 0; n < 4; n++)
    kb[n] = *(const bf16x8*)&kvb[((size_t)b_ * 64 + n * 16 + c) * 384 + h * 32 + g * 8];
  f32x4 acc[4][4] = {};
#pragma unroll
  for (int m = 0; m < 4; m++)
#pragma unroll
    for (int n = 0; n < 4; n++) acc[m][n] = mfma16(qa[m], kb[n], acc[m][n]);
  bf16x8 vb[2][2];
#pragma unroll
  for (int kk = 0; kk < 2; kk++)
#pragma unroll
    for (int nd = 0; nd < 2; nd++) {
      union { u16 u[8]; bf16x8 v; } bb;
#pragma unroll
      for (int j = 0; j < 8; j++)
        bb.u[j] = lv[(kk * 32 + g * 8 + j) * 200 + h * 32 + nd * 16 + c];
      vb[kk][nd] = bb.v;
    }
  const float* mrow = mask + (size_t)wIdx * 4096;
  f32x4 oacc[4][2] = {};
#pragma unroll
  for (int m = 0; m < 4; m++) {
#pragma unroll
    for (int r = 0; r < 4; r++) {
      int qr = m * 16 + g * 4 + r;
      int qs = qr >> 4, qh = (qr >> 2) & 3, qx = qr & 3;
      float vals[4];
#pragma unroll
      for (int n = 0; n < 4; n++) {
        int kc = n * 16 + c;
        int ks = kc >> 4, kh = (kc >> 2) & 3, kx = kc & 3;
        int idx = (qs - ks + 3) * 11 + (qh - kh + 3) * 7 + (qx - kx + 3);
        vals[n] = acc[m][n][r] + rpb[idx * 6 + h] + mrow[qr * 64 + kc];
      }
      float mx = fmaxf(fmaxf(vals[0], vals[1]), fmaxf(vals[2], vals[3]));
#pragma unroll
      for (int mm = 1; mm < 16; mm <<= 1) mx = fmaxf(mx, __shfl_xor(mx, mm, 64));
      float sum = 0.f;
#pragma unroll
      for (int n = 0; n < 4; n++) { vals[n] = __expf(vals[n] - mx); sum += vals[n]; }
#pragma unroll
      for (int mm = 1; mm < 16; mm <<= 1) sum += __shfl_xor(sum, mm, 64);
      float inv = 1.f / sum;
#pragma unroll
      for (int n = 0; n < 4; n++)
        lp[h][(g * 4 + r) * 72 + n * 16 + c] = f2bf(vals[n] * inv);
    }
#pragma unroll
    for (int kk = 0; kk < 2; kk++) {
      bf16x8 pa = *(const bf16x8*)&lp[h][c * 72 + kk * 32 + g * 8];
#pragma unroll
      for (int nd = 0; nd < 2; nd++) oacc[m][nd] = mfma16(pa, vb[kk][nd], oacc[m][nd]);
    }
  }
#pragma unroll
  for (int m = 0; m < 4; m++)
#pragma unroll
    for (int nd = 0; nd < 2; nd++)
#pragma unroll
      for (int r = 0; r < 4; r++)
        lo[(m * 16 + g * 4 + r) * 200 + h * 32 + nd * 16 + c] = f2bf(oacc[m][nd][r]);
  __syncthreads();
  f32x4 pacc[4][2] = {};
#pragma unroll
  for (int ks = 0; ks < 6; ks++) {
    bf16x8 pa[4];
#pragma unroll
    for (int m = 0; m < 4; m++)
      pa[m] = *(const bf16x8*)&lo[(m * 16 + c) * 200 + ks * 32 + g * 8];
#pragma unroll
    for (int n = 0; n < 2; n++) {
      bf16x8 pb = *(const bf16x8*)&prT[(size_t)(wv * 32 + n * 16 + c) * 192 + ks * 32 + g * 8];
#pragma unroll
      for (int m = 0; m < 4; m++) pacc[m][n] = mfma16(pa[m], pb, pacc[m][n]);
    }
  }
  int bI = b_ >> 9;
  int wS = wIdx >> 6, wH = (wIdx >> 3) & 7, wW = wIdx & 7;
  float yv[4][2][4];
#pragma unroll
  for (int m = 0; m < 4; m++)
#pragma unroll
    for (int r = 0; r < 4; r++) {
      int tok = m * 16 + g * 4 + r;
      int inS = tok >> 4, inH = (tok >> 2) & 3, inW = tok & 3;
      int s = (wS * 4 + inS + SHIFT) & 31;
      int hh = (wH * 4 + inH + SHIFT) & 31;
      int ww = (wW * 4 + inW + SHIFT) & 31;
      size_t base = ((size_t)bI * 32768 + ((size_t)s * 32 + hh) * 32 + ww) * 192;
      float sum = 0.f, sq = 0.f;
#pragma unroll
      for (int n = 0; n < 2; n++) {
        int col = wv * 32 + n * 16 + c;
        float v = pacc[m][n][r] + proj_b[col];
        po[base + col] = f2bf(v);
        float y = v + x[base + col];
        yv[m][n][r] = y;
        sum += y; sq += y * y;
      }
#pragma unroll
      for (int mm = 1; mm < 16; mm <<= 1) { sum += __shfl_xor(sum, mm, 64); sq += __shfl_xor(sq, mm, 64); }
      if (c == 0) { pf[tok * 16 + wv] = sum; pf[tok * 16 + 8 + wv] = sq; }
    }
  __syncthreads();
#pragma unroll
  for (int m = 0; m < 4; m++)
#pragma unroll
    for (int r = 0; r < 4; r++) {
      int tok = m * 16 + g * 4 + r;
      int inS = tok >> 4, inH = (tok >> 2) & 3, inW = tok & 3;
      int s = (wS * 4 + inS + SHIFT) & 31;
      int hh = (wH * 4 + inH + SHIFT) & 31;
      int ww = (wW * 4 + inW + SHIFT) & 31;
      size_t base = ((size_t)bI * 32768 + ((size_t)s * 32 + hh) * 32 + ww) * 192;
      float su = 0.f, qu = 0.f;
#pragma unroll
      for (int w6 = 0; w6 < 6; w6++) { su += pf[tok * 16 + w6]; qu += pf[tok * 16 + 8 + w6]; }
      float mu = su * (1.f / 192.f);
      float rs = rsqrtf(qu * (1.f / 192.f) - mu * mu + 1e-5f);
#pragma unroll
      for (int n = 0; n < 2; n++) {
        int col = wv * 32 + n * 16 + c;
        hn[base + col] = f2bf((yv[m][n][r] - mu) * rs * g2[col] + b2[col]);
      }
    }
}

// ---------------- K4: fused MLP, barrier-free wave-private ----------------
// Each wave owns 32 tokens end-to-end. fc1 computed TRANSPOSED (A=f1T weights,
// B=hn^T) so each lane holds 4 consecutive h1-cols -> vectorized ds_write_b64
// into a wave-PRIVATE LDS tile. No __syncthreads anywhere. fc2 accumulates
// over 8 chunks of 96 h1-cols. Weights stream from L2.
__global__ __launch_bounds__(256, 2) void k_mlp(
    const u16* __restrict__ hn, const u16* __restrict__ f1T,
    const u16* __restrict__ f2T, const float* __restrict__ b1,
    const float* __restrict__ b2f, const float* __restrict__ x,
    const u16* __restrict__ po, float* __restrict__ out) {
  __shared__ u16 lt[4][32 * 104];   // wave-private h1 chunk tiles (26.6 KB)
  int tid = threadIdx.x, l = tid & 63, wv = tid >> 6, g = l >> 4, c = l & 15;
  size_t tokbase = (size_t)blockIdx.x * 128 + wv * 32;
  u16* tile = &lt[wv][0];
  // hoist hn fragments: B-operand (hn^T) layout == row-major 8-contig reads
  bf16x8 hb[2][6];
#pragma unroll
  for (int tf = 0; tf < 2; tf++)
#pragma unroll
    for (int ks = 0; ks < 6; ks++)
      hb[tf][ks] = *(const bf16x8*)&hn[(tokbase + tf * 16 + c) * 192 + ks * 32 + g * 8];
  f32x4 acc2[12][2] = {};  // [out-frag][tok-frag], persistent
#pragma unroll 1
  for (int ko = 0; ko < 8; ko++) {
    // ---- fc1 (transposed): D1T[h1col][tok] over 96 h1-cols ----
    f32x4 acc1[6][2] = {};
#pragma unroll
    for (int ks = 0; ks < 6; ks++) {
#pragma unroll
      for (int cf = 0; cf < 6; cf++) {
        bf16x8 wa = *(const bf16x8*)&f1T[(size_t)(ko * 96 + cf * 16 + c) * 192 + ks * 32 + g * 8];
#pragma unroll
        for (int tf = 0; tf < 2; tf++) acc1[cf][tf] = mfma16(wa, hb[tf][ks], acc1[cf][tf]);
      }
    }
    // ---- gelu + pack + private LDS write (b64) ----
#pragma unroll
    for (int cf = 0; cf < 6; cf++)
#pragma unroll
      for (int tf = 0; tf < 2; tf++) {
        unsigned pk[2];
#pragma unroll
        for (int p = 0; p < 2; p++) {
          unsigned lohi[2];
#pragma unroll
          for (int q = 0; q < 2; q++) {
            int r = p * 2 + q;
            float v = acc1[cf][tf][r] + b1[ko * 96 + cf * 16 + g * 4 + r];
            float u2 = v * (1.5957691216f + 0.0713548163f * v * v);
            v = v * (1.f / (1.f + __expf(-u2)));
            lohi[q] = f2bf(v);
          }
          pk[p] = lohi[0] | (lohi[1] << 16);
        }
        *(uint2*)&tile[(tf * 16 + c) * 104 + cf * 16 + g * 4] = make_uint2(pk[0], pk[1]);
      }
    // ---- fc2 partial: K = ko*96 .. +95 (same-wave LDS dep, no barrier) ----
#pragma unroll
    for (int ck = 0; ck < 3; ck++) {
      bf16x8 a2[2];
#pragma unroll
      for (int tf = 0; tf < 2; tf++)
        a2[tf] = *(const bf16x8*)&tile[(tf * 16 + c) * 104 + ck * 32 + g * 8];
#pragma unroll
      for (int of = 0; of < 12; of++) {
        bf16x8 wb = *(const bf16x8*)&f2T[(size_t)(of * 16 + c) * 768 + ko * 96 + ck * 32 + g * 8];
#pragma unroll
        for (int tf = 0; tf < 2; tf++) acc2[of][tf] = mfma16(a2[tf], wb, acc2[of][tf]);
      }
    }
  }
  // ---- epilogue: out = fc2 + bias + x + po ----
#pragma unroll
  for (int of = 0; of < 12; of++)
#pragma unroll
    for (int tf = 0; tf < 2; tf++) {
      int col = of * 16 + c;
      float bb = b2f[col];
#pragma unroll
      for (int r = 0; r < 4; r++) {
        size_t tok = tokbase + tf * 16 + g * 4 + r;
        size_t base = tok * 192 + col;
        out[base] = acc2[of][tf][r] + bb + x[base] + bf2f(po[base]);
      }
    }
}

extern "C" void kernel_launch(void* const* d_in, const int* in_sizes, int n_in,
                              void* d_out, int out_size, void* d_ws, size_t ws_size,
                              hipStream_t stream) {
  const float* x      = (const float*)d_in[0];
  const float* mask   = (const float*)d_in[1];
  const float* skip   = (const float*)d_in[2];
  const float* x_up   = (const float*)d_in[3];
  const float* n1g    = (const float*)d_in[4];
  const float* n1b    = (const float*)d_in[5];
  const float* kv_w   = (const float*)d_in[6];
  const float* kv_b   = (const float*)d_in[7];
  const float* rpb    = (const float*)d_in[8];
  const float* proj_w = (const float*)d_in[9];
  const float* proj_b = (const float*)d_in[10];
  const float* n2g    = (const float*)d_in[11];
  const float* n2b    = (const float*)d_in[12];
  const float* fc1_w  = (const float*)d_in[13];
  const float* fc1_b  = (const float*)d_in[14];
  const float* fc2_w  = (const float*)d_in[15];
  const float* fc2_b  = (const float*)d_in[16];
  char* ws = (char*)d_ws;
  u16* kvT  = (u16*)(ws + OFF_KVWT);
  u16* prT  = (u16*)(ws + OFF_PRWT);
  u16* f1T  = (u16*)(ws + OFF_FC1WT);
  u16* f2T  = (u16*)(ws + OFF_FC2WT);
  u16* skw  = (u16*)(ws + OFF_SKW);
  u16* qw   = (u16*)(ws + OFF_QW);
  u16* kvb  = (u16*)(ws + OFF_KVB);
  u16* hn   = (u16*)(ws + OFF_HN);
  u16* po   = (u16*)(ws + OFF_PO);
  float* out = (float*)d_out;

  k_prep<<<dim3(576), dim3(256), 0, stream>>>(kv_w, proj_w, fc1_w, fc2_w, kvT, prT, f1T, f2T);
  k_ln_part<<<dim3(16384), dim3(256), 0, stream>>>(skip, x_up, n1g, n1b, skw, qw);
  k_kv<<<dim3(512, 2), dim3(256), 0, stream>>>(skw, kvT, kv_b, kvb);
  k_attn_mega<<<dim3(1024), dim3(384), 0, stream>>>(
      qw, kvb, rpb, mask, prT, proj_b, x, n2g, n2b, hn, po);
  k_mlp<<<dim3(512), dim3(256), 0, stream>>>(hn, f1T, f2T, fc1_b, fc2_b, x, po, out);
}

// Round 6
// 270.081 us; speedup vs baseline: 1.6350x; 1.6350x over previous
//
#include <hip/hip_runtime.h>
#include <math.h>

typedef unsigned short u16;
typedef __bf16 bf16x8 __attribute__((ext_vector_type(8)));
typedef float f32x4 __attribute__((ext_vector_type(4)));
typedef unsigned short u16x8 __attribute__((ext_vector_type(8)));

#define SHIFT 2

static __device__ __forceinline__ f32x4 mfma16(bf16x8 a, bf16x8 b, f32x4 c) {
  return __builtin_amdgcn_mfma_f32_16x16x32_bf16(a, b, c, 0, 0, 0);
}
static __device__ __forceinline__ u16 f2bf(float f) {
  unsigned u = __builtin_bit_cast(unsigned, f);
  unsigned r = u + 0x7fffu + ((u >> 16) & 1u);
  return (u16)(r >> 16);
}
static __device__ __forceinline__ float bf2f(u16 u) {
  unsigned v = (unsigned)u << 16;
  return __builtin_bit_cast(float, v);
}
static __device__ __forceinline__ void stage16(const u16* g, u16* lbase, int lane) {
#if __has_builtin(__builtin_amdgcn_global_load_lds)
  __builtin_amdgcn_global_load_lds(
      (const __attribute__((address_space(1))) unsigned int*)g,
      (__attribute__((address_space(3))) unsigned int*)lbase, 16, 0, 0);
#else
  *(u16x8*)(lbase + lane * 8) = *(const u16x8*)g;
#endif
}

// ---------------- workspace layout (bytes) ----------------
#define OFF_KVWT  ((size_t)0)                          // 384x192 bf16
#define OFF_PRWT  (OFF_KVWT + 384*192*2)               // 192x192
#define OFF_FC1WT (OFF_PRWT + 192*192*2)               // 768x192
#define OFF_FC2WT (OFF_FC1WT + 768*192*2)              // 192x768
#define OFF_SKW   (OFF_FC2WT + 192*768*2)              // 65536x192 bf16 (window order)
#define OFF_QW    (OFF_SKW + (size_t)65536*192*2)
#define OFF_KVB   (OFF_QW + (size_t)65536*192*2)       // 65536x384 bf16 (window order)
#define OFF_HN    (OFF_KVB + (size_t)65536*384*2)      // 65536x192 bf16 (natural)
#define OFF_PO    (OFF_HN + (size_t)65536*192*2)       // 65536x192 bf16 (natural)

// ---------------- K0: weight transpose + f32->bf16 ----------------
__global__ __launch_bounds__(256) void k_prep(
    const float* __restrict__ kv_w, const float* __restrict__ proj_w,
    const float* __restrict__ fc1_w, const float* __restrict__ fc2_w,
    u16* __restrict__ kvT, u16* __restrict__ prT,
    u16* __restrict__ f1T, u16* __restrict__ f2T) {
  int i = blockIdx.x * 256 + threadIdx.x;
  if (i < 192 * 384) kvT[(i % 384) * 192 + i / 384] = f2bf(kv_w[i]);
  if (i < 192 * 192) prT[(i % 192) * 192 + i / 192] = f2bf(proj_w[i]);
  if (i < 192 * 768) f1T[(i % 768) * 192 + i / 768] = f2bf(fc1_w[i]);
  if (i < 768 * 192) f2T[(i % 192) * 768 + i / 192] = f2bf(fc2_w[i]);
}

// ---------------- K1: LN + cyclic shift + window partition ----------------
__global__ __launch_bounds__(256) void k_ln_part(
    const float* __restrict__ skip, const float* __restrict__ x_up,
    const float* __restrict__ gam, const float* __restrict__ bet,
    u16* __restrict__ skw, u16* __restrict__ qw) {
  int row = blockIdx.x * 4 + (threadIdx.x >> 6);
  int lane = threadIdx.x & 63;
  const float* sp = skip + (size_t)row * 192;
  const float* qp = x_up + (size_t)row * 192;
  float sv[3], qv[3], ss = 0.f, qs = 0.f;
#pragma unroll
  for (int j = 0; j < 3; j++) {
    sv[j] = sp[lane + 64 * j]; qv[j] = qp[lane + 64 * j];
    ss += sv[j]; qs += qv[j];
  }
#pragma unroll
  for (int m = 1; m < 64; m <<= 1) { ss += __shfl_xor(ss, m, 64); qs += __shfl_xor(qs, m, 64); }
  float sm = ss * (1.f / 192.f), qm = qs * (1.f / 192.f);
  float s2 = 0.f, q2 = 0.f;
#pragma unroll
  for (int j = 0; j < 3; j++) { float d = sv[j] - sm; s2 += d * d; d = qv[j] - qm; q2 += d * d; }
#pragma unroll
  for (int m = 1; m < 64; m <<= 1) { s2 += __shfl_xor(s2, m, 64); q2 += __shfl_xor(q2, m, 64); }
  float sr = rsqrtf(s2 * (1.f / 192.f) + 1e-5f), qr = rsqrtf(q2 * (1.f / 192.f) + 1e-5f);
  int b = row >> 15, l = row & 32767;
  int s = l >> 10, h = (l >> 5) & 31, w = l & 31;
  int s_ = (s - SHIFT) & 31, h_ = (h - SHIFT) & 31, w_ = (w - SHIFT) & 31;
  int wIdx = ((s_ >> 2) * 8 + (h_ >> 2)) * 8 + (w_ >> 2);
  int n = ((s_ & 3) * 4 + (h_ & 3)) * 4 + (w_ & 3);
  size_t orow = ((size_t)(b * 512 + wIdx) * 64 + n) * 192;
  const float scale = 0.17677669529663687f;  // 32^-0.5
#pragma unroll
  for (int j = 0; j < 3; j++) {
    int cc = lane + 64 * j;
    float gg = gam[cc], bb = bet[cc];
    skw[orow + cc] = f2bf((sv[j] - sm) * sr * gg + bb);
    qw[orow + cc]  = f2bf(((qv[j] - qm) * qr * gg + bb) * scale);
  }
}

// ---------------- K2: kv GEMM (m97-style, reverted: best measured) ----------------
__global__ __launch_bounds__(256) void k_kv(
    const u16* __restrict__ A, const u16* __restrict__ BT,
    const float* __restrict__ bias, u16* __restrict__ outh) {
  __shared__ u16 lds[(128 + 128) * 64];
  int mb = blockIdx.x, nb = blockIdx.y;
  int tid = threadIdx.x, w = tid >> 6, l = tid & 63;
  int wr = w >> 1, wc = w & 1, g = l >> 4, c = l & 15;
  f32x4 acc[4][4] = {};
  for (int ks = 0; ks < 3; ks++) {
    if (ks) __syncthreads();
    int k0 = ks * 64;
#pragma unroll
    for (int i = 0; i < 4; i++) {
      int s = w * 4 + i;
      stage16(&A[(size_t)(mb * 128 + s * 8 + (l >> 3)) * 192 + k0 + (l & 7) * 8],
              &lds[s * 512], l);
      stage16(&BT[(size_t)(nb * 128 + s * 8 + (l >> 3)) * 192 + k0 + (l & 7) * 8],
              &lds[8192 + s * 512], l);
    }
    __syncthreads();
#pragma unroll
    for (int kk = 0; kk < 2; kk++) {
      bf16x8 a[4];
#pragma unroll
      for (int m = 0; m < 4; m++)
        a[m] = *(const bf16x8*)&lds[(wr * 64 + m * 16 + c) * 64 + kk * 32 + g * 8];
#pragma unroll
      for (int n = 0; n < 4; n++) {
        bf16x8 b = *(const bf16x8*)&lds[8192 + (wc * 64 + n * 16 + c) * 64 + kk * 32 + g * 8];
#pragma unroll
        for (int m = 0; m < 4; m++) acc[m][n] = mfma16(a[m], b, acc[m][n]);
      }
    }
  }
#pragma unroll
  for (int m = 0; m < 4; m++)
#pragma unroll
    for (int n = 0; n < 4; n++)
#pragma unroll
      for (int r = 0; r < 4; r++) {
        int row = mb * 128 + wr * 64 + m * 16 + g * 4 + r;
        int col = nb * 128 + wc * 64 + n * 16 + c;
        outh[(size_t)row * 384 + col] = f2bf(acc[m][n][r] + bias[col]);
      }
}

// ---------------- K3: fused attention + proj + residual + LN2 -----------------
__global__ __launch_bounds__(384) void k_attn_mega(
    const u16* __restrict__ qw, const u16* __restrict__ kvb,
    const float* __restrict__ rpb, const float* __restrict__ mask,
    const u16* __restrict__ prT, const float* __restrict__ proj_b,
    const float* __restrict__ x, const float* __restrict__ g2,
    const float* __restrict__ b2, u16* __restrict__ hn, u16* __restrict__ po) {
  __shared__ u16 lv[64 * 200];
  __shared__ u16 lp[6][16 * 72];
  __shared__ u16 lo[64 * 200];
  __shared__ float pf[64 * 16];
  int b_ = blockIdx.x, wIdx = b_ & 511;
  int tid = threadIdx.x, l = tid & 63, wv = tid >> 6, g = l >> 4, c = l & 15;
#pragma unroll
  for (int i = 0; i < 4; i++) {
    int cid = tid + i * 384;
    int row = cid / 24, ch = cid % 24;
    *(u16x8*)&lv[row * 200 + ch * 8] =
        *(const u16x8*)&kvb[((size_t)b_ * 64 + row) * 384 + 192 + ch * 8];
  }
  __syncthreads();
  int h = wv;
  bf16x8 qa[4], kb[4];
#pragma unroll
  for (int m = 0; m < 4; m++)
    qa[m] = *(const bf16x8*)&qw[((size_t)b_ * 64 + m * 16 + c) * 192 + h * 32 + g * 8];
#pragma unroll
  for (int n = 0; n < 4; n++)
    kb[n] = *(const bf16x8*)&kvb[((size_t)b_ * 64 + n * 16 + c) * 384 + h * 32 + g * 8];
  f32x4 acc[4][4] = {};
#pragma unroll
  for (int m = 0; m < 4; m++)
#pragma unroll
    for (int n = 0; n < 4; n++) acc[m][n] = mfma16(qa[m], kb[n], acc[m][n]);
  bf16x8 vb[2][2];
#pragma unroll
  for (int kk = 0; kk < 2; kk++)
#pragma unroll
    for (int nd = 0; nd < 2; nd++) {
      union { u16 u[8]; bf16x8 v; } bb;
#pragma unroll
      for (int j = 0; j < 8; j++)
        bb.u[j] = lv[(kk * 32 + g * 8 + j) * 200 + h * 32 + nd * 16 + c];
      vb[kk][nd] = bb.v;
    }
  const float* mrow = mask + (size_t)wIdx * 4096;
  f32x4 oacc[4][2] = {};
#pragma unroll
  for (int m = 0; m < 4; m++) {
#pragma unroll
    for (int r = 0; r < 4; r++) {
      int qr = m * 16 + g * 4 + r;
      int qs = qr >> 4, qh = (qr >> 2) & 3, qx = qr & 3;
      float vals[4];
#pragma unroll
      for (int n = 0; n < 4; n++) {
        int kc = n * 16 + c;
        int ks = kc >> 4, kh = (kc >> 2) & 3, kx = kc & 3;
        int idx = (qs - ks + 3) * 11 + (qh - kh + 3) * 7 + (qx - kx + 3);
        vals[n] = acc[m][n][r] + rpb[idx * 6 + h] + mrow[qr * 64 + kc];
      }
      float mx = fmaxf(fmaxf(vals[0], vals[1]), fmaxf(vals[2], vals[3]));
#pragma unroll
      for (int mm = 1; mm < 16; mm <<= 1) mx = fmaxf(mx, __shfl_xor(mx, mm, 64));
      float sum = 0.f;
#pragma unroll
      for (int n = 0; n < 4; n++) { vals[n] = __expf(vals[n] - mx); sum += vals[n]; }
#pragma unroll
      for (int mm = 1; mm < 16; mm <<= 1) sum += __shfl_xor(sum, mm, 64);
      float inv = 1.f / sum;
#pragma unroll
      for (int n = 0; n < 4; n++)
        lp[h][(g * 4 + r) * 72 + n * 16 + c] = f2bf(vals[n] * inv);
    }
#pragma unroll
    for (int kk = 0; kk < 2; kk++) {
      bf16x8 pa = *(const bf16x8*)&lp[h][c * 72 + kk * 32 + g * 8];
#pragma unroll
      for (int nd = 0; nd < 2; nd++) oacc[m][nd] = mfma16(pa, vb[kk][nd], oacc[m][nd]);
    }
  }
#pragma unroll
  for (int m = 0; m < 4; m++)
#pragma unroll
    for (int nd = 0; nd < 2; nd++)
#pragma unroll
      for (int r = 0; r < 4; r++)
        lo[(m * 16 + g * 4 + r) * 200 + h * 32 + nd * 16 + c] = f2bf(oacc[m][nd][r]);
  __syncthreads();
  f32x4 pacc[4][2] = {};
#pragma unroll
  for (int ks = 0; ks < 6; ks++) {
    bf16x8 pa[4];
#pragma unroll
    for (int m = 0; m < 4; m++)
      pa[m] = *(const bf16x8*)&lo[(m * 16 + c) * 200 + ks * 32 + g * 8];
#pragma unroll
    for (int n = 0; n < 2; n++) {
      bf16x8 pb = *(const bf16x8*)&prT[(size_t)(wv * 32 + n * 16 + c) * 192 + ks * 32 + g * 8];
#pragma unroll
      for (int m = 0; m < 4; m++) pacc[m][n] = mfma16(pa[m], pb, pacc[m][n]);
    }
  }
  int bI = b_ >> 9;
  int wS = wIdx >> 6, wH = (wIdx >> 3) & 7, wW = wIdx & 7;
  float yv[4][2][4];
#pragma unroll
  for (int m = 0; m < 4; m++)
#pragma unroll
    for (int r = 0; r < 4; r++) {
      int tok = m * 16 + g * 4 + r;
      int inS = tok >> 4, inH = (tok >> 2) & 3, inW = tok & 3;
      int s = (wS * 4 + inS + SHIFT) & 31;
      int hh = (wH * 4 + inH + SHIFT) & 31;
      int ww = (wW * 4 + inW + SHIFT) & 31;
      size_t base = ((size_t)bI * 32768 + ((size_t)s * 32 + hh) * 32 + ww) * 192;
      float sum = 0.f, sq = 0.f;
#pragma unroll
      for (int n = 0; n < 2; n++) {
        int col = wv * 32 + n * 16 + c;
        float v = pacc[m][n][r] + proj_b[col];
        po[base + col] = f2bf(v);
        float y = v + x[base + col];
        yv[m][n][r] = y;
        sum += y; sq += y * y;
      }
#pragma unroll
      for (int mm = 1; mm < 16; mm <<= 1) { sum += __shfl_xor(sum, mm, 64); sq += __shfl_xor(sq, mm, 64); }
      if (c == 0) { pf[tok * 16 + wv] = sum; pf[tok * 16 + 8 + wv] = sq; }
    }
  __syncthreads();
#pragma unroll
  for (int m = 0; m < 4; m++)
#pragma unroll
    for (int r = 0; r < 4; r++) {
      int tok = m * 16 + g * 4 + r;
      int inS = tok >> 4, inH = (tok >> 2) & 3, inW = tok & 3;
      int s = (wS * 4 + inS + SHIFT) & 31;
      int hh = (wH * 4 + inH + SHIFT) & 31;
      int ww = (wW * 4 + inW + SHIFT) & 31;
      size_t base = ((size_t)bI * 32768 + ((size_t)s * 32 + hh) * 32 + ww) * 192;
      float su = 0.f, qu = 0.f;
#pragma unroll
      for (int w6 = 0; w6 < 6; w6++) { su += pf[tok * 16 + w6]; qu += pf[tok * 16 + 8 + w6]; }
      float mu = su * (1.f / 192.f);
      float rs = rsqrtf(qu * (1.f / 192.f) - mu * mu + 1e-5f);
#pragma unroll
      for (int n = 0; n < 2; n++) {
        int col = wv * 32 + n * 16 + c;
        hn[base + col] = f2bf((yv[m][n][r] - mu) * rs * g2[col] + b2[col]);
      }
    }
}

// ---------------- K4: fused MLP, LDS-staged weights (async), chunked K ---------
// Block = 64 tokens, 4 waves. 12 chunks of 64 h1-cols. Per chunk both weight
// tiles staged into LDS via global_load_lds with XOR-swizzled per-lane SOURCE
// (LDS dest stays linear; read side applies the same XOR) -> conflict-free
// ds_read_b128 and ZERO global loads in the MFMA dependency chain.
// hn token fragments hoisted into registers once (96 VGPR). LDS 58.4 KB ->
// 2 blocks/CU.
__global__ __launch_bounds__(256, 2) void k_mlp(
    const u16* __restrict__ hn, const u16* __restrict__ f1T,
    const u16* __restrict__ f2T, const float* __restrict__ b1,
    const float* __restrict__ b2f, const float* __restrict__ x,
    const u16* __restrict__ po, float* __restrict__ out) {
  __shared__ u16 lds[29184];          // f1c 12288 | f2c 12288 | h1c 4608
  u16* f1c = lds;
  u16* f2c = lds + 12288;
  u16* h1c = lds + 24576;
  int tid = threadIdx.x, l = tid & 63, wv = tid >> 6, g = l >> 4, c = l & 15;
  size_t tokbase = (size_t)blockIdx.x * 64;

  // ---- stage hn tile (64x192) into f1c region, swizzled source ----
#pragma unroll
  for (int i = 0; i < 6; i++) {
    int CI = i * 256 + wv * 64 + l;
    int row = CI / 24, chp = CI % 24;
    int sch = (chp & 24) | ((chp ^ row) & 7);
    stage16(hn + (tokbase + row) * 192 + sch * 8, f1c + (i * 256 + wv * 64) * 8, l);
  }
  __syncthreads();
  // ---- hoist hn B-fragments: hb[tf][ks], lane c = token tf*16+c ----
  bf16x8 hb[4][6];
#pragma unroll
  for (int tf = 0; tf < 4; tf++)
#pragma unroll
    for (int ks = 0; ks < 6; ks++) {
      int ch = ks * 4 + g;
      int chp = (ch & 24) | ((ch ^ c) & 7);
      hb[tf][ks] = *(const bf16x8*)&f1c[(tf * 16 + c) * 192 + chp * 8];
    }
  f32x4 acc2[3][4] = {};  // [out-frag][tok-frag]
#pragma unroll 1
  for (int ko = 0; ko < 12; ko++) {
    __syncthreads();  // prior chunk's reads (or hb hoist) done before overwrite
    // stage f1T rows [ko*64, +64) x 192  (64 rows x 24 chunks)
#pragma unroll
    for (int i = 0; i < 6; i++) {
      int CI = i * 256 + wv * 64 + l;
      int row = CI / 24, chp = CI % 24;
      int sch = (chp & 24) | ((chp ^ row) & 7);
      stage16(f1T + (size_t)(ko * 64 + row) * 192 + sch * 8,
              f1c + (i * 256 + wv * 64) * 8, l);
    }
    // stage f2T [192 rows] x K-slice [ko*64, +64)  (192 rows x 8 chunks)
#pragma unroll
    for (int i = 0; i < 6; i++) {
      int CI = i * 256 + wv * 64 + l;
      int row = CI >> 3, chp = CI & 7;
      int sch = chp ^ (row & 7);
      stage16(f2T + (size_t)row * 768 + ko * 64 + sch * 8,
              f2c + (i * 256 + wv * 64) * 8, l);
    }
    __syncthreads();  // stages drained (syncthreads waits vmcnt(0))
    // ---- fc1 transposed: D1[h1col][tok]; wave owns h1-cols wv*16..+15 ----
    f32x4 acc1[4] = {};
#pragma unroll
    for (int ks = 0; ks < 6; ks++) {
      int ch = ks * 4 + g;
      int chp = (ch & 24) | ((ch ^ c) & 7);
      bf16x8 wa = *(const bf16x8*)&f1c[(wv * 16 + c) * 192 + chp * 8];
#pragma unroll
      for (int tf = 0; tf < 4; tf++) acc1[tf] = mfma16(wa, hb[tf][ks], acc1[tf]);
    }
    // gelu + pack; lane holds h1-cols wv*16+g*4..+3 (consecutive) for tok tf*16+c
    float4 b1v = *(const float4*)&b1[ko * 64 + wv * 16 + g * 4];
#pragma unroll
    for (int tf = 0; tf < 4; tf++) {
      unsigned pk[2];
#pragma unroll
      for (int p = 0; p < 2; p++) {
        unsigned lohi[2];
#pragma unroll
        for (int q = 0; q < 2; q++) {
          int r = p * 2 + q;
          float v = acc1[tf][r] + (r == 0 ? b1v.x : r == 1 ? b1v.y : r == 2 ? b1v.z : b1v.w);
          float u2 = v * (1.5957691216f + 0.0713548163f * v * v);
          v = v * (1.f / (1.f + __expf(-u2)));
          lohi[q] = f2bf(v);
        }
        pk[p] = lohi[0] | (lohi[1] << 16);
      }
      *(uint2*)&h1c[(tf * 16 + c) * 72 + wv * 16 + g * 4] = make_uint2(pk[0], pk[1]);
    }
    __syncthreads();  // h1 chunk ready
    // ---- fc2 partial: D2[tok][out]; wave owns out-cols wv*48..+47 ----
#pragma unroll
    for (int ck = 0; ck < 2; ck++) {
      bf16x8 a2[4];
#pragma unroll
      for (int tf = 0; tf < 4; tf++)
        a2[tf] = *(const bf16x8*)&h1c[(tf * 16 + c) * 72 + ck * 32 + g * 8];
#pragma unroll
      for (int of = 0; of < 3; of++) {
        int ch = ck * 4 + g;
        int chp = ch ^ (c & 7);
        bf16x8 wb = *(const bf16x8*)&f2c[(wv * 48 + of * 16 + c) * 64 + chp * 8];
#pragma unroll
        for (int tf = 0; tf < 4; tf++) acc2[of][tf] = mfma16(a2[tf], wb, acc2[of][tf]);
      }
    }
  }
  // ---- epilogue: out = fc2 + bias + x + po ----
#pragma unroll
  for (int of = 0; of < 3; of++)
#pragma unroll
    for (int tf = 0; tf < 4; tf++) {
      int col = wv * 48 + of * 16 + c;
      float bb = b2f[col];
#pragma unroll
      for (int r = 0; r < 4; r++) {
        size_t tok = tokbase + tf * 16 + g * 4 + r;
        size_t base = tok * 192 + col;
        out[base] = acc2[of][tf][r] + bb + x[base] + bf2f(po[base]);
      }
    }
}

extern "C" void kernel_launch(void* const* d_in, const int* in_sizes, int n_in,
                              void* d_out, int out_size, void* d_ws, size_t ws_size,
                              hipStream_t stream) {
  const float* x      = (const float*)d_in[0];
  const float* mask   = (const float*)d_in[1];
  const float* skip   = (const float*)d_in[2];
  const float* x_up   = (const float*)d_in[3];
  const float* n1g    = (const float*)d_in[4];
  const float* n1b    = (const float*)d_in[5];
  const float* kv_w   = (const float*)d_in[6];
  const float* kv_b   = (const float*)d_in[7];
  const float* rpb    = (const float*)d_in[8];
  const float* proj_w = (const float*)d_in[9];
  const float* proj_b = (const float*)d_in[10];
  const float* n2g    = (const float*)d_in[11];
  const float* n2b    = (const float*)d_in[12];
  const float* fc1_w  = (const float*)d_in[13];
  const float* fc1_b  = (const float*)d_in[14];
  const float* fc2_w  = (const float*)d_in[15];
  const float* fc2_b  = (const float*)d_in[16];
  char* ws = (char*)d_ws;
  u16* kvT  = (u16*)(ws + OFF_KVWT);
  u16* prT  = (u16*)(ws + OFF_PRWT);
  u16* f1T  = (u16*)(ws + OFF_FC1WT);
  u16* f2T  = (u16*)(ws + OFF_FC2WT);
  u16* skw  = (u16*)(ws + OFF_SKW);
  u16* qw   = (u16*)(ws + OFF_QW);
  u16* kvb  = (u16*)(ws + OFF_KVB);
  u16* hn   = (u16*)(ws + OFF_HN);
  u16* po   = (u16*)(ws + OFF_PO);
  float* out = (float*)d_out;

  k_prep<<<dim3(576), dim3(256), 0, stream>>>(kv_w, proj_w, fc1_w, fc2_w, kvT, prT, f1T, f2T);
  k_ln_part<<<dim3(16384), dim3(256), 0, stream>>>(skip, x_up, n1g, n1b, skw, qw);
  k_kv<<<dim3(512, 3), dim3(256), 0, stream>>>(skw, kvT, kv_b, kvb);
  k_attn_mega<<<dim3(1024), dim3(384), 0, stream>>>(
      qw, kvb, rpb, mask, prT, proj_b, x, n2g, n2b, hn, po);
  k_mlp<<<dim3(1024), dim3(256), 0, stream>>>(hn, f1T, f2T, fc1_b, fc2_b, x, po, out);
}

// Round 8
// 260.842 us; speedup vs baseline: 1.6929x; 1.0354x over previous
//
#include <hip/hip_runtime.h>
#include <math.h>

typedef unsigned short u16;
typedef __bf16 bf16x8 __attribute__((ext_vector_type(8)));
typedef float f32x4 __attribute__((ext_vector_type(4)));
typedef unsigned short u16x8 __attribute__((ext_vector_type(8)));

#define SHIFT 2

static __device__ __forceinline__ f32x4 mfma16(bf16x8 a, bf16x8 b, f32x4 c) {
  return __builtin_amdgcn_mfma_f32_16x16x32_bf16(a, b, c, 0, 0, 0);
}
static __device__ __forceinline__ u16 f2bf(float f) {
  unsigned u = __builtin_bit_cast(unsigned, f);
  unsigned r = u + 0x7fffu + ((u >> 16) & 1u);
  return (u16)(r >> 16);
}
static __device__ __forceinline__ float bf2f(u16 u) {
  unsigned v = (unsigned)u << 16;
  return __builtin_bit_cast(float, v);
}
static __device__ __forceinline__ void stage16(const u16* g, u16* lbase, int lane) {
#if __has_builtin(__builtin_amdgcn_global_load_lds)
  __builtin_amdgcn_global_load_lds(
      (const __attribute__((address_space(1))) unsigned int*)g,
      (__attribute__((address_space(3))) unsigned int*)lbase, 16, 0, 0);
#else
  *(u16x8*)(lbase + lane * 8) = *(const u16x8*)g;
#endif
}

// ---------------- workspace layout (bytes) ----------------
#define OFF_KVWT  ((size_t)0)                          // 384x192 bf16
#define OFF_PRWT  (OFF_KVWT + 384*192*2)               // 192x192
#define OFF_FC1WT (OFF_PRWT + 192*192*2)               // 768x192
#define OFF_FC2WT (OFF_FC1WT + 768*192*2)              // 192x768
#define OFF_SKW   (OFF_FC2WT + 192*768*2)              // 65536x192 bf16 (window order)
#define OFF_QW    (OFF_SKW + (size_t)65536*192*2)
#define OFF_KVB   (OFF_QW + (size_t)65536*192*2)       // 65536x384 bf16 (window order)
#define OFF_HN    (OFF_KVB + (size_t)65536*384*2)      // 65536x192 bf16 (natural)
#define OFF_PO    (OFF_HN + (size_t)65536*192*2)       // 65536x192 bf16 (natural)

// ---------------- K0: weight transpose + f32->bf16 ----------------
__global__ __launch_bounds__(256) void k_prep(
    const float* __restrict__ kv_w, const float* __restrict__ proj_w,
    const float* __restrict__ fc1_w, const float* __restrict__ fc2_w,
    u16* __restrict__ kvT, u16* __restrict__ prT,
    u16* __restrict__ f1T, u16* __restrict__ f2T) {
  int i = blockIdx.x * 256 + threadIdx.x;
  if (i < 192 * 384) kvT[(i % 384) * 192 + i / 384] = f2bf(kv_w[i]);
  if (i < 192 * 192) prT[(i % 192) * 192 + i / 192] = f2bf(proj_w[i]);
  if (i < 192 * 768) f1T[(i % 768) * 192 + i / 768] = f2bf(fc1_w[i]);
  if (i < 768 * 192) f2T[(i % 192) * 768 + i / 192] = f2bf(fc2_w[i]);
}

// ---------------- K1: LN + cyclic shift + window partition ----------------
__global__ __launch_bounds__(256) void k_ln_part(
    const float* __restrict__ skip, const float* __restrict__ x_up,
    const float* __restrict__ gam, const float* __restrict__ bet,
    u16* __restrict__ skw, u16* __restrict__ qw) {
  int row = blockIdx.x * 4 + (threadIdx.x >> 6);
  int lane = threadIdx.x & 63;
  const float* sp = skip + (size_t)row * 192;
  const float* qp = x_up + (size_t)row * 192;
  float sv[3], qv[3], ss = 0.f, qs = 0.f;
#pragma unroll
  for (int j = 0; j < 3; j++) {
    sv[j] = sp[lane + 64 * j]; qv[j] = qp[lane + 64 * j];
    ss += sv[j]; qs += qv[j];
  }
#pragma unroll
  for (int m = 1; m < 64; m <<= 1) { ss += __shfl_xor(ss, m, 64); qs += __shfl_xor(qs, m, 64); }
  float sm = ss * (1.f / 192.f), qm = qs * (1.f / 192.f);
  float s2 = 0.f, q2 = 0.f;
#pragma unroll
  for (int j = 0; j < 3; j++) { float d = sv[j] - sm; s2 += d * d; d = qv[j] - qm; q2 += d * d; }
#pragma unroll
  for (int m = 1; m < 64; m <<= 1) { s2 += __shfl_xor(s2, m, 64); q2 += __shfl_xor(q2, m, 64); }
  float sr = rsqrtf(s2 * (1.f / 192.f) + 1e-5f), qr = rsqrtf(q2 * (1.f / 192.f) + 1e-5f);
  int b = row >> 15, l = row & 32767;
  int s = l >> 10, h = (l >> 5) & 31, w = l & 31;
  int s_ = (s - SHIFT) & 31, h_ = (h - SHIFT) & 31, w_ = (w - SHIFT) & 31;
  int wIdx = ((s_ >> 2) * 8 + (h_ >> 2)) * 8 + (w_ >> 2);
  int n = ((s_ & 3) * 4 + (h_ & 3)) * 4 + (w_ & 3);
  size_t orow = ((size_t)(b * 512 + wIdx) * 64 + n) * 192;
  const float scale = 0.17677669529663687f;  // 32^-0.5
#pragma unroll
  for (int j = 0; j < 3; j++) {
    int cc = lane + 64 * j;
    float gg = gam[cc], bb = bet[cc];
    skw[orow + cc] = f2bf((sv[j] - sm) * sr * gg + bb);
    qw[orow + cc]  = f2bf(((qv[j] - qm) * qr * gg + bb) * scale);
  }
}

// ---------------- K2: kv GEMM — weights staged once (async+swizzled), then
// barrier-free streaming: A direct from global (L3-resident), B from LDS. ----
__global__ __launch_bounds__(256, 2) void k_kv(
    const u16* __restrict__ A, const u16* __restrict__ BT,
    const float* __restrict__ bias, u16* __restrict__ outh) {
  __shared__ u16 lw[192 * 192];  // 73.7 KB: kvT rows [nb*192, +192)
  int mb = blockIdx.x, nb = blockIdx.y;
  int tid = threadIdx.x, l = tid & 63, wv = tid >> 6, g = l >> 4, c = l & 15;
  int wr = wv >> 1, wc = wv & 1;
#pragma unroll
  for (int i = 0; i < 18; i++) {
    int CI = i * 256 + tid;
    int row = CI / 24, ch = CI % 24;
    int sch = (ch & 24) | ((ch ^ row) & 7);
    stage16(BT + (size_t)(nb * 192 + row) * 192 + sch * 8, lw + (i * 256 + wv * 64) * 8, l);
  }
  __syncthreads();
  f32x4 acc[4][6] = {};
#pragma unroll
  for (int ks = 0; ks < 6; ks++) {
    bf16x8 a[4];
#pragma unroll
    for (int m = 0; m < 4; m++)
      a[m] = *(const bf16x8*)&A[(size_t)(mb * 128 + wr * 64 + m * 16 + c) * 192 + ks * 32 + g * 8];
#pragma unroll
    for (int n = 0; n < 6; n++) {
      int col = wc * 96 + n * 16 + c;
      int ch = ks * 4 + g;
      int chp = (ch & 24) | ((ch ^ col) & 7);
      bf16x8 b = *(const bf16x8*)&lw[col * 192 + chp * 8];
#pragma unroll
      for (int m = 0; m < 4; m++) acc[m][n] = mfma16(a[m], b, acc[m][n]);
    }
  }
#pragma unroll
  for (int n = 0; n < 6; n++)
#pragma unroll
    for (int m = 0; m < 4; m++) {
      int col = nb * 192 + wc * 96 + n * 16 + c;
      float bb = bias[col];
#pragma unroll
      for (int r = 0; r < 4; r++) {
        int row = mb * 128 + wr * 64 + m * 16 + g * 4 + r;
        outh[(size_t)row * 384 + col] = f2bf(acc[m][n][r] + bb);
      }
    }
}

// ---------------- K3: fused attention + proj + residual + LN2 -----------------
// mask (f32, padded stride 68) + rpb (f32) staged to LDS up front; V via async
// global_load_lds (FIXED: 24 chunks/row); lo aliases lv, pf aliases lp.
// No global loads in the softmax/PV/proj chains.
__global__ __launch_bounds__(384, 4) void k_attn_mega(
    const u16* __restrict__ qw, const u16* __restrict__ kvb,
    const float* __restrict__ rpb, const float* __restrict__ mask,
    const u16* __restrict__ prT, const float* __restrict__ proj_b,
    const float* __restrict__ x, const float* __restrict__ g2,
    const float* __restrict__ b2, u16* __restrict__ hn, u16* __restrict__ po) {
  __shared__ __align__(16) char smem[25600 + 13824 + 17408 + 8256];
  u16* lv = (u16*)smem;                        // [64][192], unpadded (stage16)
  u16* lo = (u16*)smem;                        // [64][200], aliases lv
  u16* lp = (u16*)(smem + 25600);              // [6][16*72]
  float* pf = (float*)(smem + 25600);          // aliases lp (epilogue only)
  float* lmaskf = (float*)(smem + 25600 + 13824);        // [64][68] f32
  float* lrpbf  = (float*)(smem + 25600 + 13824 + 17408); // 2058 f32
  int b_ = blockIdx.x, wIdx = b_ & 511;
  int tid = threadIdx.x, l = tid & 63, wv = tid >> 6, g = l >> 4, c = l & 15;
  int h = wv;
  // ---- (1) V tile async -> LDS: 64 rows x 24 chunks of 16B (exact) ----
#pragma unroll
  for (int i = 0; i < 4; i++) {
    int CI = i * 384 + tid;
    int row = CI / 24, ch = CI % 24;
    stage16(kvb + ((size_t)b_ * 64 + row) * 384 + 192 + ch * 8,
            lv + (i * 384 + wv * 64) * 8, l);
  }
  // ---- (2) Q/K fragments hoisted (issue now, consumed after barrier) ----
  bf16x8 qa[4], kb[4];
#pragma unroll
  for (int m = 0; m < 4; m++)
    qa[m] = *(const bf16x8*)&qw[((size_t)b_ * 64 + m * 16 + c) * 192 + h * 32 + g * 8];
#pragma unroll
  for (int n = 0; n < 4; n++)
    kb[n] = *(const bf16x8*)&kvb[((size_t)b_ * 64 + n * 16 + c) * 384 + h * 32 + g * 8];
  // ---- (3) mask + rpb stage (f32, full precision) ----
  const float* mrow = mask + (size_t)wIdx * 4096;
#pragma unroll
  for (int i = 0; i < 3; i++) {
    int idx = i * 384 + tid;
    if (idx < 1024) {
      float4 mv = *(const float4*)&mrow[idx * 4];
      int row = idx >> 4, c4 = idx & 15;
      *(float4*)&lmaskf[row * 68 + c4 * 4] = mv;
    }
  }
#pragma unroll
  for (int i = 0; i < 6; i++) {
    int idx = i * 384 + tid;
    if (idx < 2058) lrpbf[idx] = rpb[idx];
  }
  __syncthreads();  // drains stage16 + ds_writes
  // ---- (5) V fragments from LDS ----
  bf16x8 vb[2][2];
#pragma unroll
  for (int kk = 0; kk < 2; kk++)
#pragma unroll
    for (int nd = 0; nd < 2; nd++) {
      union { u16 u[8]; bf16x8 v; } bb;
#pragma unroll
      for (int j = 0; j < 8; j++)
        bb.u[j] = lv[(kk * 32 + g * 8 + j) * 192 + h * 32 + nd * 16 + c];
      vb[kk][nd] = bb.v;
    }
  __syncthreads();  // lv dead everywhere -> lo region may be written
  // ---- (7) QK^T ----
  f32x4 acc[4][4] = {};
#pragma unroll
  for (int m = 0; m < 4; m++)
#pragma unroll
    for (int n = 0; n < 4; n++) acc[m][n] = mfma16(qa[m], kb[n], acc[m][n]);
  // ---- (8) softmax (LDS-only operands) + PV ----
  f32x4 oacc[4][2] = {};
#pragma unroll
  for (int m = 0; m < 4; m++) {
#pragma unroll
    for (int r = 0; r < 4; r++) {
      int qr = m * 16 + g * 4 + r;
      int qs = qr >> 4, qh = (qr >> 2) & 3, qx = qr & 3;
      float vals[4];
#pragma unroll
      for (int n = 0; n < 4; n++) {
        int kc = n * 16 + c;
        int ks = kc >> 4, kh = (kc >> 2) & 3, kx = kc & 3;
        int idx = (qs - ks + 3) * 11 + (qh - kh + 3) * 7 + (qx - kx + 3);
        vals[n] = acc[m][n][r] + lrpbf[idx * 6 + h] + lmaskf[qr * 68 + kc];
      }
      float mx = fmaxf(fmaxf(vals[0], vals[1]), fmaxf(vals[2], vals[3]));
#pragma unroll
      for (int mm = 1; mm < 16; mm <<= 1) mx = fmaxf(mx, __shfl_xor(mx, mm, 64));
      float sum = 0.f;
#pragma unroll
      for (int n = 0; n < 4; n++) { vals[n] = __expf(vals[n] - mx); sum += vals[n]; }
#pragma unroll
      for (int mm = 1; mm < 16; mm <<= 1) sum += __shfl_xor(sum, mm, 64);
      float inv = 1.f / sum;
#pragma unroll
      for (int n = 0; n < 4; n++)
        lp[h * 1152 + (g * 4 + r) * 72 + n * 16 + c] = f2bf(vals[n] * inv);
    }
#pragma unroll
    for (int kk = 0; kk < 2; kk++) {
      bf16x8 pa = *(const bf16x8*)&lp[h * 1152 + c * 72 + kk * 32 + g * 8];
#pragma unroll
      for (int nd = 0; nd < 2; nd++) oacc[m][nd] = mfma16(pa, vb[kk][nd], oacc[m][nd]);
    }
  }
  // ---- (9) attention output -> lo (aliases lv; safe after barrier 6) ----
#pragma unroll
  for (int m = 0; m < 4; m++)
#pragma unroll
    for (int nd = 0; nd < 2; nd++)
#pragma unroll
      for (int r = 0; r < 4; r++)
        lo[(m * 16 + g * 4 + r) * 200 + h * 32 + nd * 16 + c] = f2bf(oacc[m][nd][r]);
  __syncthreads();
  // ---- (11) proj ----
  f32x4 pacc[4][2] = {};
#pragma unroll
  for (int ks = 0; ks < 6; ks++) {
    bf16x8 pa[4];
#pragma unroll
    for (int m = 0; m < 4; m++)
      pa[m] = *(const bf16x8*)&lo[(m * 16 + c) * 200 + ks * 32 + g * 8];
#pragma unroll
    for (int n = 0; n < 2; n++) {
      bf16x8 pb = *(const bf16x8*)&prT[(size_t)(wv * 32 + n * 16 + c) * 192 + ks * 32 + g * 8];
#pragma unroll
      for (int m = 0; m < 4; m++) pacc[m][n] = mfma16(pa[m], pb, pacc[m][n]);
    }
  }
  // ---- (12) epilogue: scatter + residual + LN2 (pf aliases lp) ----
  int bI = b_ >> 9;
  int wS = wIdx >> 6, wH = (wIdx >> 3) & 7, wW = wIdx & 7;
  float yv[4][2][4];
#pragma unroll
  for (int m = 0; m < 4; m++)
#pragma unroll
    for (int r = 0; r < 4; r++) {
      int tok = m * 16 + g * 4 + r;
      int inS = tok >> 4, inH = (tok >> 2) & 3, inW = tok & 3;
      int s = (wS * 4 + inS + SHIFT) & 31;
      int hh = (wH * 4 + inH + SHIFT) & 31;
      int ww = (wW * 4 + inW + SHIFT) & 31;
      size_t base = ((size_t)bI * 32768 + ((size_t)s * 32 + hh) * 32 + ww) * 192;
      float sum = 0.f, sq = 0.f;
#pragma unroll
      for (int n = 0; n < 2; n++) {
        int col = wv * 32 + n * 16 + c;
        float v = pacc[m][n][r] + proj_b[col];
        po[base + col] = f2bf(v);
        float y = v + x[base + col];
        yv[m][n][r] = y;
        sum += y; sq += y * y;
      }
#pragma unroll
      for (int mm = 1; mm < 16; mm <<= 1) { sum += __shfl_xor(sum, mm, 64); sq += __shfl_xor(sq, mm, 64); }
      if (c == 0) { pf[tok * 16 + wv] = sum; pf[tok * 16 + 8 + wv] = sq; }
    }
  __syncthreads();
#pragma unroll
  for (int m = 0; m < 4; m++)
#pragma unroll
    for (int r = 0; r < 4; r++) {
      int tok = m * 16 + g * 4 + r;
      int inS = tok >> 4, inH = (tok >> 2) & 3, inW = tok & 3;
      int s = (wS * 4 + inS + SHIFT) & 31;
      int hh = (wH * 4 + inH + SHIFT) & 31;
      int ww = (wW * 4 + inW + SHIFT) & 31;
      size_t base = ((size_t)bI * 32768 + ((size_t)s * 32 + hh) * 32 + ww) * 192;
      float su = 0.f, qu = 0.f;
#pragma unroll
      for (int w6 = 0; w6 < 6; w6++) { su += pf[tok * 16 + w6]; qu += pf[tok * 16 + 8 + w6]; }
      float mu = su * (1.f / 192.f);
      float rs = rsqrtf(qu * (1.f / 192.f) - mu * mu + 1e-5f);
#pragma unroll
      for (int n = 0; n < 2; n++) {
        int col = wv * 32 + n * 16 + c;
        hn[base + col] = f2bf((yv[m][n][r] - mu) * rs * g2[col] + b2[col]);
      }
    }
}

// ---------------- K4: fused MLP, LDS-staged weights (async), chunked K ---------
__global__ __launch_bounds__(256, 2) void k_mlp(
    const u16* __restrict__ hn, const u16* __restrict__ f1T,
    const u16* __restrict__ f2T, const float* __restrict__ b1,
    const float* __restrict__ b2f, const float* __restrict__ x,
    const u16* __restrict__ po, float* __restrict__ out) {
  __shared__ u16 lds[29184];          // f1c 12288 | f2c 12288 | h1c 4608
  u16* f1c = lds;
  u16* f2c = lds + 12288;
  u16* h1c = lds + 24576;
  int tid = threadIdx.x, l = tid & 63, wv = tid >> 6, g = l >> 4, c = l & 15;
  size_t tokbase = (size_t)blockIdx.x * 64;
#pragma unroll
  for (int i = 0; i < 6; i++) {
    int CI = i * 256 + wv * 64 + l;
    int row = CI / 24, chp = CI % 24;
    int sch = (chp & 24) | ((chp ^ row) & 7);
    stage16(hn + (tokbase + row) * 192 + sch * 8, f1c + (i * 256 + wv * 64) * 8, l);
  }
  __syncthreads();
  bf16x8 hb[4][6];
#pragma unroll
  for (int tf = 0; tf < 4; tf++)
#pragma unroll
    for (int ks = 0; ks < 6; ks++) {
      int ch = ks * 4 + g;
      int chp = (ch & 24) | ((ch ^ c) & 7);
      hb[tf][ks] = *(const bf16x8*)&f1c[(tf * 16 + c) * 192 + chp * 8];
    }
  f32x4 acc2[3][4] = {};
#pragma unroll 1
  for (int ko = 0; ko < 12; ko++) {
    __syncthreads();
#pragma unroll
    for (int i = 0; i < 6; i++) {
      int CI = i * 256 + wv * 64 + l;
      int row = CI / 24, chp = CI % 24;
      int sch = (chp & 24) | ((chp ^ row) & 7);
      stage16(f1T + (size_t)(ko * 64 + row) * 192 + sch * 8,
              f1c + (i * 256 + wv * 64) * 8, l);
    }
#pragma unroll
    for (int i = 0; i < 6; i++) {
      int CI = i * 256 + wv * 64 + l;
      int row = CI >> 3, chp = CI & 7;
      int sch = chp ^ (row & 7);
      stage16(f2T + (size_t)row * 768 + ko * 64 + sch * 8,
              f2c + (i * 256 + wv * 64) * 8, l);
    }
    __syncthreads();
    f32x4 acc1[4] = {};
#pragma unroll
    for (int ks = 0; ks < 6; ks++) {
      int ch = ks * 4 + g;
      int chp = (ch & 24) | ((ch ^ c) & 7);
      bf16x8 wa = *(const bf16x8*)&f1c[(wv * 16 + c) * 192 + chp * 8];
#pragma unroll
      for (int tf = 0; tf < 4; tf++) acc1[tf] = mfma16(wa, hb[tf][ks], acc1[tf]);
    }
    float4 b1v = *(const float4*)&b1[ko * 64 + wv * 16 + g * 4];
#pragma unroll
    for (int tf = 0; tf < 4; tf++) {
      unsigned pk[2];
#pragma unroll
      for (int p = 0; p < 2; p++) {
        unsigned lohi[2];
#pragma unroll
        for (int q = 0; q < 2; q++) {
          int r = p * 2 + q;
          float v = acc1[tf][r] + (r == 0 ? b1v.x : r == 1 ? b1v.y : r == 2 ? b1v.z : b1v.w);
          float u2 = v * (1.5957691216f + 0.0713548163f * v * v);
          v = v * (1.f / (1.f + __expf(-u2)));
          lohi[q] = f2bf(v);
        }
        pk[p] = lohi[0] | (lohi[1] << 16);
      }
      *(uint2*)&h1c[(tf * 16 + c) * 72 + wv * 16 + g * 4] = make_uint2(pk[0], pk[1]);
    }
    __syncthreads();
#pragma unroll
    for (int ck = 0; ck < 2; ck++) {
      bf16x8 a2[4];
#pragma unroll
      for (int tf = 0; tf < 4; tf++)
        a2[tf] = *(const bf16x8*)&h1c[(tf * 16 + c) * 72 + ck * 32 + g * 8];
#pragma unroll
      for (int of = 0; of < 3; of++) {
        int ch = ck * 4 + g;
        int chp = ch ^ (c & 7);
        bf16x8 wb = *(const bf16x8*)&f2c[(wv * 48 + of * 16 + c) * 64 + chp * 8];
#pragma unroll
        for (int tf = 0; tf < 4; tf++) acc2[of][tf] = mfma16(a2[tf], wb, acc2[of][tf]);
      }
    }
  }
#pragma unroll
  for (int of = 0; of < 3; of++)
#pragma unroll
    for (int tf = 0; tf < 4; tf++) {
      int col = wv * 48 + of * 16 + c;
      float bb = b2f[col];
#pragma unroll
      for (int r = 0; r < 4; r++) {
        size_t tok = tokbase + tf * 16 + g * 4 + r;
        size_t base = tok * 192 + col;
        out[base] = acc2[of][tf][r] + bb + x[base] + bf2f(po[base]);
      }
    }
}

extern "C" void kernel_launch(void* const* d_in, const int* in_sizes, int n_in,
                              void* d_out, int out_size, void* d_ws, size_t ws_size,
                              hipStream_t stream) {
  const float* x      = (const float*)d_in[0];
  const float* mask   = (const float*)d_in[1];
  const float* skip   = (const float*)d_in[2];
  const float* x_up   = (const float*)d_in[3];
  const float* n1g    = (const float*)d_in[4];
  const float* n1b    = (const float*)d_in[5];
  const float* kv_w   = (const float*)d_in[6];
  const float* kv_b   = (const float*)d_in[7];
  const float* rpb    = (const float*)d_in[8];
  const float* proj_w = (const float*)d_in[9];
  const float* proj_b = (const float*)d_in[10];
  const float* n2g    = (const float*)d_in[11];
  const float* n2b    = (const float*)d_in[12];
  const float* fc1_w  = (const float*)d_in[13];
  const float* fc1_b  = (const float*)d_in[14];
  const float* fc2_w  = (const float*)d_in[15];
  const float* fc2_b  = (const float*)d_in[16];
  char* ws = (char*)d_ws;
  u16* kvT  = (u16*)(ws + OFF_KVWT);
  u16* prT  = (u16*)(ws + OFF_PRWT);
  u16* f1T  = (u16*)(ws + OFF_FC1WT);
  u16* f2T  = (u16*)(ws + OFF_FC2WT);
  u16* skw  = (u16*)(ws + OFF_SKW);
  u16* qw   = (u16*)(ws + OFF_QW);
  u16* kvb  = (u16*)(ws + OFF_KVB);
  u16* hn   = (u16*)(ws + OFF_HN);
  u16* po   = (u16*)(ws + OFF_PO);
  float* out = (float*)d_out;

  k_prep<<<dim3(576), dim3(256), 0, stream>>>(kv_w, proj_w, fc1_w, fc2_w, kvT, prT, f1T, f2T);
  k_ln_part<<<dim3(16384), dim3(256), 0, stream>>>(skip, x_up, n1g, n1b, skw, qw);
  k_kv<<<dim3(512, 2), dim3(256), 0, stream>>>(skw, kvT, kv_b, kvb);
  k_attn_mega<<<dim3(1024), dim3(384), 0, stream>>>(
      qw, kvb, rpb, mask, prT, proj_b, x, n2g, n2b, hn, po);
  k_mlp<<<dim3(1024), dim3(256), 0, stream>>>(hn, f1T, f2T, fc1_b, fc2_b, x, po, out);
}